// Round 3
// baseline (555.924 us; speedup 1.0000x reference)
//
#include <hip/hip_runtime.h>
#include <stdint.h>

// BiRealConv2d: y = conv2d(sign(x), scale[o]*sign(w)), NCHW, 3x3, pad 1.
// v3: XNOR-popcount retired — v_bcnt throughput (quarter-rate: measured 329k
//     busy cyc/SIMD vs 322k predicted at 8cy/bcnt) put a ~118us floor on the
//     VALU formulation. Rewritten as exact i8 GEMM on the matrix cores:
//     C[px,o] = A[o,K]^ (weights, M-dim) x B[K,px] (pixels), K = 128ch x 9taps,
//     v_mfma_i32_32x32x32_i8 (4404 TOPS ubench -> 27us MFMA floor; 205MB
//     output write -> ~33us BW floor).
//     x stored as padded NHWC i8 (halo = 0 -> contributes exactly 0: no corr
//     table). Weights pre-shuffled to fragment-contiguous wpack layout.

#define HH 112
#define WW 112
#define CC 128
#define OO 128
#define NN 32
#define HP 114
#define WP 114
#define ROWB (WP * 128)              // 14592 B per padded row
#define PLANEB ((size_t)HP * ROWB)   // 1,663,488 B per image

typedef int int4v  __attribute__((ext_vector_type(4)));
typedef int int16v __attribute__((ext_vector_type(16)));

// ---------------- pass 1: fp32 NCHW -> padded NHWC i8 (+1/-1, halo 0) -------------
// Per block: one padded row (n, hp). Coalesced float4 reads along w, LDS [c][w]
// transpose (row stride 116 -> conflict-free dword writes), 256B-contiguous
// NHWC dword stores. Halo rows/columns zeroed in-kernel (no memset launch).
__global__ __launch_bounds__(256) void pack_x_kernel(const float* __restrict__ x,
                                                     char* __restrict__ xi8) {
  int t = threadIdx.x;
  int hp = blockIdx.x;             // 0..113
  int n = blockIdx.y;
  char* dst = xi8 + (size_t)n * PLANEB + (size_t)hp * ROWB;
  int4v z; z.x = 0; z.y = 0; z.z = 0; z.w = 0;
  if (hp == 0 || hp == HP - 1) {   // h-halo row: all zeros
    for (int i = t; i < ROWB / 16; i += 256) ((int4v*)dst)[i] = z;
    return;
  }
  if (t < 8)       ((int4v*)dst)[t] = z;                       // w-halo pixel 0
  else if (t < 16) ((int4v*)(dst + 113 * 128))[t - 8] = z;     // w-halo pixel 113
  int h = hp - 1;
  __shared__ char lds[128 * 116];  // [c][w], stride 116 (odd/4 -> no conflicts)
  const float* src = x + ((size_t)n * CC * HH + h) * WW;       // + c*HH*WW
#pragma unroll
  for (int iter = 0; iter < 14; iter++) {
    int it = iter * 256 + t;       // 0..3583 = 128c x 28 float4
    int c = it / 28, w4 = it - c * 28;
    float4 v = *(const float4*)(src + (size_t)c * (HH * WW) + w4 * 4);
    unsigned int d = (v.x > 0.f ? 0x01u : 0xFFu)
                   | (v.y > 0.f ? 0x0100u : 0xFF00u)
                   | (v.z > 0.f ? 0x010000u : 0xFF0000u)
                   | (v.w > 0.f ? 0x01000000u : 0xFF000000u);
    *(unsigned int*)(lds + c * 116 + w4 * 4) = d;
  }
  __syncthreads();
  int c4 = t & 31, wq = t >> 5;    // store lanes: 32 c-dwords x 2 pixels = 256B
#pragma unroll
  for (int iter = 0; iter < 14; iter++) {
    int w = iter * 8 + wq;
    unsigned int b0 = (unsigned char)lds[(c4 * 4 + 0) * 116 + w];
    unsigned int b1 = (unsigned char)lds[(c4 * 4 + 1) * 116 + w];
    unsigned int b2 = (unsigned char)lds[(c4 * 4 + 2) * 116 + w];
    unsigned int b3 = (unsigned char)lds[(c4 * 4 + 3) * 116 + w];
    *(unsigned int*)(dst + (w + 1) * 128 + c4 * 4) = b0 | (b1 << 8) | (b2 << 16) | (b3 << 24);
  }
}

// ---------------- pass 0: weight scale + fragment-contiguous i8 wpack -------------
// wpack[(tap*4+ks)*2 + hf][o][16B]: lane l of an A-frag (o = l&31 + og*32,
// hf = l>>5) reads 16 contiguous bytes = channels ks*32 + hf*16 .. +15.
__global__ __launch_bounds__(256) void prep_w_kernel(const float* __restrict__ wt,
                                                     char* __restrict__ wpack,
                                                     float* __restrict__ scale) {
  int o = blockIdx.x;
  const float* wo = wt + (size_t)o * (CC * 9);
  __shared__ float red[256];
  int t = threadIdx.x;
  float s = 0.f;
  for (int idx = t; idx < CC * 9; idx += 256) {  // OIHW: idx = c*9 + tap
    float v = wo[idx];
    s += fabsf(v);
    int c = idx / 9, tap = idx - c * 9;
    int ks = c >> 5, hf = (c >> 4) & 1, b = c & 15;
    wpack[(((tap * 4 + ks) * 2 + hf) * 128 + o) * 16 + b] = v > 0.f ? 1 : -1;
  }
  red[t] = s;
  __syncthreads();
  for (int st = 128; st > 0; st >>= 1) {
    if (t < st) red[t] += red[t + st];
    __syncthreads();
  }
  if (t == 0) scale[o] = red[0] * (1.0f / 1152.0f);
}

// ---------------- pass 2: i8 MFMA conv --------------------------------------------
// Block: 128 flat pixels x all 128 o. Wave og = t>>6: 32 o x 128 px (4 C-tiles,
// 4 independent acc chains). A-frag (weights) loaded once per (tap,ks), reused
// across the 4 pixel tiles. D layout (32x32): col=lane&31=pixel,
// row=(r&3)+8*(r>>2)+4*hf = o -> stores are 2x128B segments into NCHW.
__global__ __launch_bounds__(256, 3) void conv_kernel(const char* __restrict__ xi8,
                                                      const char* __restrict__ wpack,
                                                      const float* __restrict__ scale,
                                                      float* __restrict__ out) {
  int t = threadIdx.x;
  int og = t >> 6;                 // wave-uniform o-group (32 o)
  int l = t & 63;
  int l31 = l & 31, hf = l >> 5;
  int bx = blockIdx.x;             // 0..3135 (12544 px/image = 98 blocks x 32 n)
  int n = bx / 98;
  int prow = (bx - n * 98) * 128;
  const char* xb = xi8 + (size_t)n * PLANEB;
  int voff[4];
#pragma unroll
  for (int ct = 0; ct < 4; ct++) {
    int p = prow + ct * 32 + l31;  // flat pixel; row crossings fine (per-lane h,w)
    int h = p / 112;
    int w = p - h * 112;
    voff[ct] = (h * WP + w) * 128 + hf * 16;   // tap (dh,dw in 0..2) adds the pad shift
  }
  int woff = hf * 2048 + (og * 32 + l31) * 16;
  int16v acc0 = {0}, acc1 = {0}, acc2 = {0}, acc3 = {0};
#pragma unroll
  for (int tap = 0; tap < 9; tap++) {
    const int dh = tap / 3, dw = tap % 3;
    const char* rowd = xb + dh * ROWB + dw * 128;
#pragma unroll
    for (int ks = 0; ks < 4; ks++) {
      int4v a = *(const int4v*)(wpack + (tap * 4 + ks) * 4096 + woff);
      int4v b0 = *(const int4v*)(rowd + voff[0] + ks * 32);
      int4v b1 = *(const int4v*)(rowd + voff[1] + ks * 32);
      int4v b2 = *(const int4v*)(rowd + voff[2] + ks * 32);
      int4v b3 = *(const int4v*)(rowd + voff[3] + ks * 32);
      acc0 = __builtin_amdgcn_mfma_i32_32x32x32_i8(a, b0, acc0, 0, 0, 0);
      acc1 = __builtin_amdgcn_mfma_i32_32x32x32_i8(a, b1, acc1, 0, 0, 0);
      acc2 = __builtin_amdgcn_mfma_i32_32x32x32_i8(a, b2, acc2, 0, 0, 0);
      ac3:;
      acc3 = __builtin_amdgcn_mfma_i32_32x32x32_i8(a, b3, acc3, 0, 0, 0);
    }
  }
  int obase = og * 32;
  float sc[16];
#pragma unroll
  for (int r = 0; r < 16; r++)
    sc[r] = scale[obase + (r & 3) + 8 * (r >> 2) + 4 * hf];
#pragma unroll
  for (int r = 0; r < 16; r++) {
    int o = obase + (r & 3) + 8 * (r >> 2) + 4 * hf;
    float* op = out + (size_t)(n * OO + o) * (HH * WW) + prow + l31;
    op[0]  = sc[r] * (float)acc0[r];
    op[32] = sc[r] * (float)acc1[r];
    op[64] = sc[r] * (float)acc2[r];
    op[96] = sc[r] * (float)acc3[r];
  }
}

extern "C" void kernel_launch(void* const* d_in, const int* in_sizes, int n_in,
                              void* d_out, int out_size, void* d_ws, size_t ws_size,
                              hipStream_t stream) {
  const float* x  = (const float*)d_in[0];
  const float* wt = (const float*)d_in[1];
  float* out = (float*)d_out;

  char* ws = (char*)d_ws;
  char* xi8 = ws;                                   // 32 * 1,663,488 = 53,231,616 B
  char* wpack = ws + (size_t)NN * PLANEB;           // 147,456 B
  float* scale = (float*)(wpack + (size_t)9 * 4 * 2 * 128 * 16);  // 512 B

  hipLaunchKernelGGL(pack_x_kernel, dim3(HP, NN), dim3(256), 0, stream, x, xi8);
  hipLaunchKernelGGL(prep_w_kernel, dim3(OO), dim3(256), 0, stream, wt, wpack, scale);
  hipLaunchKernelGGL(conv_kernel, dim3(3136), dim3(256), 0, stream,
                     xi8, wpack, scale, out);
}

// Round 5
// 424.140 us; speedup vs baseline: 1.3107x; 1.3107x over previous
//
#include <hip/hip_runtime.h>
#include <stdint.h>

// BiRealConv2d: y = conv2d(sign(x), scale[o]*sign(w)), NCHW, 3x3, pad 1.
// v4 (resubmit; round-4 bench was an infra failure, no kernel verdict):
//     v3 (i8 MFMA, correct but latency-bound: MfmaUtil 9.7%, VALUBusy 3.6%,
//     occupancy 40% -- global B-loads ~200cyc never hidden) -> LDS-staged x.
//     Block = (n, output row h) x 128 o; stages padded rows h..h+2 into LDS
//     (49.5 KB, cols 114..131 zero), K-loop reads B via ds_read_b128.
//     Bank fix: xi8 is stored GLOBALLY pre-swizzled (byte ^= ((col&7)<<4),
//     a within-128B permutation) so staging is a straight copy and only the
//     ds_read applies the XOR -> 2-way bank aliasing (free, m136).
//     A (wpack, 147 KB) stays global: L2-hot, coalesced 2x512B per load.

#define HH 112
#define WW 112
#define CC 128
#define OO 128
#define NN 32
#define HP 114
#define WP 114
#define ROWB (WP * 128)              // 14592 B per padded row in xi8
#define PLANEB ((size_t)HP * ROWB)   // 1,663,488 B per image
#define LROWB (132 * 128)            // 16896 B LDS row (cols 0..131; >=114 zero)
#define LTOT  (3 * LROWB)            // 50688 B
#define NI4   (LTOT / 16)            // 3168 int4 slots
#define LROW4 (LROWB / 16)           // 1056
#define GROW4 (ROWB / 16)            // 912

typedef int int4v  __attribute__((ext_vector_type(4)));
typedef int int16v __attribute__((ext_vector_type(16)));

// ---------------- pass 1: fp32 NCHW -> padded NHWC i8 (+1/-1, halo 0) -------------
// Same structure as v3 (coalesced float4 reads, LDS [c][w] transpose), but data
// stores land at the SWIZZLED address: dword (c4*4) ^ ((col&7)<<4) within the
// col's 128B block. Halo stores are zeros -> permutation-invariant.
__global__ __launch_bounds__(256) void pack_x_kernel(const float* __restrict__ x,
                                                     char* __restrict__ xi8) {
  int t = threadIdx.x;
  int hp = blockIdx.x;             // 0..113
  int n = blockIdx.y;
  char* dst = xi8 + (size_t)n * PLANEB + (size_t)hp * ROWB;
  int4v z; z.x = 0; z.y = 0; z.z = 0; z.w = 0;
  if (hp == 0 || hp == HP - 1) {   // h-halo row: all zeros
    for (int i = t; i < ROWB / 16; i += 256) ((int4v*)dst)[i] = z;
    return;
  }
  if (t < 8)       ((int4v*)dst)[t] = z;                       // w-halo col 0
  else if (t < 16) ((int4v*)(dst + 113 * 128))[t - 8] = z;     // w-halo col 113
  int h = hp - 1;
  __shared__ char lds[128 * 116];  // [c][w], stride 116
  const float* src = x + ((size_t)n * CC * HH + h) * WW;       // + c*HH*WW
#pragma unroll
  for (int iter = 0; iter < 14; iter++) {
    int it = iter * 256 + t;       // 0..3583 = 128c x 28 float4
    int c = it / 28, w4 = it - c * 28;
    float4 v = *(const float4*)(src + (size_t)c * (HH * WW) + w4 * 4);
    unsigned int d = (v.x > 0.f ? 0x01u : 0xFFu)
                   | (v.y > 0.f ? 0x0100u : 0xFF00u)
                   | (v.z > 0.f ? 0x010000u : 0xFF0000u)
                   | (v.w > 0.f ? 0x01000000u : 0xFF000000u);
    *(unsigned int*)(lds + c * 116 + w4 * 4) = d;
  }
  __syncthreads();
  int c4 = t & 31, wq = t >> 5;    // 32 c-dwords x 8 pixels per pass
#pragma unroll
  for (int iter = 0; iter < 14; iter++) {
    int w = iter * 8 + wq;
    unsigned int b0 = (unsigned char)lds[(c4 * 4 + 0) * 116 + w];
    unsigned int b1 = (unsigned char)lds[(c4 * 4 + 1) * 116 + w];
    unsigned int b2 = (unsigned char)lds[(c4 * 4 + 2) * 116 + w];
    unsigned int b3 = (unsigned char)lds[(c4 * 4 + 3) * 116 + w];
    int p = w + 1;                 // padded col
    *(unsigned int*)(dst + p * 128 + ((c4 * 4) ^ ((p & 7) << 4))) =
        b0 | (b1 << 8) | (b2 << 16) | (b3 << 24);
  }
}

// ---------------- pass 0: weight scale + fragment-contiguous i8 wpack -------------
// wpack[(tap*4+ks)*2 + hf][o][16B]: lane l of an A-frag (o = l&31 + og*32,
// hf = l>>5) reads 16 contiguous bytes = channels ks*32 + hf*16 .. +15.
__global__ __launch_bounds__(256) void prep_w_kernel(const float* __restrict__ wt,
                                                     char* __restrict__ wpack,
                                                     float* __restrict__ scale) {
  int o = blockIdx.x;
  const float* wo = wt + (size_t)o * (CC * 9);
  __shared__ float red[256];
  int t = threadIdx.x;
  float s = 0.f;
  for (int idx = t; idx < CC * 9; idx += 256) {  // OIHW: idx = c*9 + tap
    float v = wo[idx];
    s += fabsf(v);
    int c = idx / 9, tap = idx - c * 9;
    int ks = c >> 5, hf = (c >> 4) & 1, b = c & 15;
    wpack[(((tap * 4 + ks) * 2 + hf) * 128 + o) * 16 + b] = v > 0.f ? 1 : -1;
  }
  red[t] = s;
  __syncthreads();
  for (int st = 128; st > 0; st >>= 1) {
    if (t < st) red[t] += red[t + st];
    __syncthreads();
  }
  if (t == 0) scale[o] = red[0] * (1.0f / 1152.0f);
}

// ---------------- pass 2: i8 MFMA conv, LDS-staged B ------------------------------
// Wave og: 32 o x 112 px (4 tiles of 32 px, last 16 lanes of tile 3 masked on
// store). D layout (32x32): col=lane&31=pixel, row=(r&3)+8*(r>>2)+4*hf = o.
__global__ __launch_bounds__(256, 3) void conv_kernel(const char* __restrict__ xi8,
                                                      const char* __restrict__ wpack,
                                                      const float* __restrict__ scale,
                                                      float* __restrict__ out) {
  __shared__ __align__(16) char xl[LTOT];
  int t = threadIdx.x;
  int h = blockIdx.x;              // output row -> padded rows h..h+2
  int n = blockIdx.y;
  const char* gbase = xi8 + (size_t)n * PLANEB + (size_t)h * ROWB;
  // stage 3 rows (straight copy; xi8 already swizzled) + zero cols 114..131
#pragma unroll
  for (int i = 0; i < 13; i++) {
    int idx = t + i * 256;
    if (idx < NI4) {
      int r = idx / LROW4, j = idx - r * LROW4;
      int4v v; v.x = 0; v.y = 0; v.z = 0; v.w = 0;
      if (j < GROW4) v = *(const int4v*)(gbase + (size_t)r * ROWB + (size_t)j * 16);
      *(int4v*)(xl + (size_t)idx * 16) = v;
    }
  }
  __syncthreads();

  int og = t >> 6;                 // wave-uniform o-group (32 o)
  int l = t & 63;
  int l31 = l & 31, hf = l >> 5;
  int woff = hf * 2048 + (og * 32 + l31) * 16;
  int16v acc0 = {0}, acc1 = {0}, acc2 = {0}, acc3 = {0};
#pragma unroll
  for (int tap = 0; tap < 9; tap++) {
    const int dh = tap / 3, dw = tap % 3;
    const int p0 = l31 + dw;                 // tile-0 padded col; tiles add 32 (&7-invariant)
    const int key = (p0 & 7) << 4;
    const char* bbase = xl + dh * LROWB + p0 * 128;
#pragma unroll
    for (int ks = 0; ks < 4; ks++) {
      int4v a = *(const int4v*)(wpack + (tap * 4 + ks) * 4096 + woff);
      const char* bp = bbase + ((ks * 32 + hf * 16) ^ key);
      int4v b0 = *(const int4v*)(bp);
      int4v b1 = *(const int4v*)(bp + 32 * 128);
      int4v b2 = *(const int4v*)(bp + 64 * 128);
      int4v b3 = *(const int4v*)(bp + 96 * 128);
      acc0 = __builtin_amdgcn_mfma_i32_32x32x32_i8(a, b0, acc0, 0, 0, 0);
      acc1 = __builtin_amdgcn_mfma_i32_32x32x32_i8(a, b1, acc1, 0, 0, 0);
      acc2 = __builtin_amdgcn_mfma_i32_32x32x32_i8(a, b2, acc2, 0, 0, 0);
      acc3 = __builtin_amdgcn_mfma_i32_32x32x32_i8(a, b3, acc3, 0, 0, 0);
    }
  }

  int obase = og * 32;
  size_t outb = (size_t)(n * OO) * (HH * WW) + (size_t)h * WW + l31;
#pragma unroll
  for (int r = 0; r < 16; r++) {
    int o = obase + (r & 3) + 8 * (r >> 2) + 4 * hf;
    float s = scale[o];
    float* op = out + outb + (size_t)o * (HH * WW);
    op[0]  = s * (float)acc0[r];
    op[32] = s * (float)acc1[r];
    op[64] = s * (float)acc2[r];
    if (l31 < 16) op[96] = s * (float)acc3[r];   // w = 96+l31 valid only < 112
  }
}

extern "C" void kernel_launch(void* const* d_in, const int* in_sizes, int n_in,
                              void* d_out, int out_size, void* d_ws, size_t ws_size,
                              hipStream_t stream) {
  const float* x  = (const float*)d_in[0];
  const float* wt = (const float*)d_in[1];
  float* out = (float*)d_out;

  char* ws = (char*)d_ws;
  char* xi8 = ws;                                   // 32 * 1,663,488 = 53,231,616 B
  char* wpack = ws + (size_t)NN * PLANEB;           // 147,456 B
  float* scale = (float*)(wpack + (size_t)9 * 4 * 2 * 128 * 16);  // 512 B

  hipLaunchKernelGGL(pack_x_kernel, dim3(HP, NN), dim3(256), 0, stream, x, xi8);
  hipLaunchKernelGGL(prep_w_kernel, dim3(OO), dim3(256), 0, stream, wt, wpack, scale);
  hipLaunchKernelGGL(conv_kernel, dim3(HH, NN), dim3(256), 0, stream,
                     xi8, wpack, scale, out);
}